// Round 11
// baseline (364.742 us; speedup 1.0000x reference)
//
#include <hip/hip_runtime.h>

#define BB 32
#define TT 256
#define NN 128
#define DD 64
#define KSTR 136   // dL column stride in halves: 272B -> 16B-aligned b128 frags

typedef _Float16 f16x4 __attribute__((ext_vector_type(4)));
typedef _Float16 f16x8 __attribute__((ext_vector_type(8)));
typedef float    f32x4v __attribute__((ext_vector_type(4)));

#define FMA4(acc, s, v) do { \
    acc.x = __builtin_fmaf((s), (v).x, acc.x); \
    acc.y = __builtin_fmaf((s), (v).y, acc.y); \
    acc.z = __builtin_fmaf((s), (v).z, acc.z); \
    acc.w = __builtin_fmaf((s), (v).w, acc.w); } while (0)

// barrier that drains only LDS (lgkmcnt) — keeps global loads / stores in flight
#define LBAR() do { asm volatile("s_waitcnt lgkmcnt(0)" ::: "memory"); \
                    __builtin_amdgcn_s_barrier(); } while (0)

// ---------------------------------------------------------------- K1: fused build + blocked GJ inverse -> invM^T
// (validated r8-r10 structure, unchanged)
__global__ __launch_bounds__(256) void k_prep(const float* __restrict__ A,
                                              float* __restrict__ invMt) {
    __shared__ __align__(16) float sM[NN][132];   // 67.5 KB
    __shared__ __align__(16) float rB[16][NN];    // 8 KB; rB[0] hosts deg first
    __shared__ float fcol[2][NN];                 // pivot-column scratch (dbuf)
    __shared__ float akj[2][16];                  // pivot-row-entry scratch (dbuf)
    const int b = blockIdx.x;
    const int tid = threadIdx.x;
    const float* Ab = A + b * NN * NN;

    if (tid < NN) {
        float s = 0.f;
        const float4* A4 = (const float4*)(Ab + tid * NN);
        #pragma unroll 4
        for (int j = 0; j < NN / 4; ++j) { float4 v = A4[j]; s += v.x + v.y + v.z + v.w; }
        rB[0][tid] = s;
    }
    __syncthreads();
    for (int flat = tid; flat < NN * NN; flat += 256) {
        const int i = flat >> 7, j = flat & 127;
        const float a = Ab[flat];
        sM[i][j] = -a + ((i == j) ? (rB[0][i] + 1.1f) : 0.f);
    }
    __syncthreads();

    const int jl = tid & 15;     // panel column (phase 1)
    const int rg = tid >> 4;     // row group: rows rg*8..rg*8+8 (phase 1)
    const int qq = tid & 31;     // column quad (phase 2)
    const int rh = tid >> 5;     // row half-set (phase 2)

    for (int pk = 0; pk < 8; ++pk) {
        const int K0 = pk << 4;

        // ---- phase 1: register-carried panel GJ
        float v[8];
        #pragma unroll
        for (int r = 0; r < 8; ++r) v[r] = sM[rg * 8 + r][K0 + jl];

        for (int kl = 0; kl < 16; ++kl) {
            const int k = K0 + kl;
            const int buf = kl & 1;
            if (jl == kl) {                       // publish current pivot column
                #pragma unroll
                for (int r = 0; r < 8; ++r) fcol[buf][rg * 8 + r] = v[r];
            }
            if (rg == (k >> 3)) {                 // publish pivot-row entry for col jl
                float pick = v[0];
                #pragma unroll
                for (int r = 1; r < 8; ++r) if ((k & 7) == r) pick = v[r];
                akj[buf][jl] = pick;
            }
            __syncthreads();
            const float pv = akj[buf][kl];        // pivot value (broadcast)
            const float a  = akj[buf][jl];        // pivot row, this thread's col
            float fc[8];
            #pragma unroll
            for (int r = 0; r < 8; ++r) fc[r] = fcol[buf][rg * 8 + r];
            const float p  = 1.0f / pv;
            const float ap = a * p;
            #pragma unroll
            for (int r = 0; r < 8; ++r) {
                const int i = rg * 8 + r;
                float nv;
                if (jl == kl) nv = (i == k) ? p  : -fc[r] * p;
                else          nv = (i == k) ? ap : v[r] - fc[r] * ap;
                v[r] = nv;
            }
        }
        #pragma unroll
        for (int r = 0; r < 8; ++r) sM[rg * 8 + r][K0 + jl] = v[r];
        __syncthreads();

        // ---- stage old row-block R = sM[K0..K0+16)[all cols]
        for (int q = tid; q < 16 * NN / 4; q += 256) {
            const int m = q >> 5, j4 = (q & 31) << 2;
            *(float4*)&rB[m][j4] = *(float4*)&sM[K0 + m][j4];
        }
        __syncthreads();

        // ---- phase 2: rank-16 update of non-panel columns
        const int pq0 = K0 >> 2;
        const bool act = (qq < pq0) || (qq >= pq0 + 4);
        float4 Rq[16];
        if (act) {
            #pragma unroll
            for (int m = 0; m < 16; ++m) Rq[m] = *(float4*)&rB[m][qq << 2];
        }
        #pragma unroll 2
        for (int r = 0; r < 16; ++r) {
            const int i = rh * 16 + r;
            float4 c0 = *(float4*)&sM[i][K0];
            float4 c1 = *(float4*)&sM[i][K0 + 4];
            float4 c2 = *(float4*)&sM[i][K0 + 8];
            float4 c3 = *(float4*)&sM[i][K0 + 12];
            if (act) {
                const bool prow = (i >= K0) && (i < K0 + 16);
                float4 acc;
                if (prow) { acc.x = acc.y = acc.z = acc.w = 0.f; }
                else        acc = *(float4*)&sM[i][qq << 2];
                FMA4(acc, c0.x, Rq[0]);  FMA4(acc, c0.y, Rq[1]);
                FMA4(acc, c0.z, Rq[2]);  FMA4(acc, c0.w, Rq[3]);
                FMA4(acc, c1.x, Rq[4]);  FMA4(acc, c1.y, Rq[5]);
                FMA4(acc, c1.z, Rq[6]);  FMA4(acc, c1.w, Rq[7]);
                FMA4(acc, c2.x, Rq[8]);  FMA4(acc, c2.y, Rq[9]);
                FMA4(acc, c2.z, Rq[10]); FMA4(acc, c2.w, Rq[11]);
                FMA4(acc, c3.x, Rq[12]); FMA4(acc, c3.y, Rq[13]);
                FMA4(acc, c3.z, Rq[14]); FMA4(acc, c3.w, Rq[15]);
                *(float4*)&sM[i][qq << 2] = acc;
            }
        }
        __syncthreads();
    }
    // write transposed: invMt[k][i] = invM[i][k]
    for (int flat = tid; flat < NN * NN; flat += 256) {
        const int kk = flat >> 7, ii = flat & 127;
        invMt[b * NN * NN + flat] = sM[ii][kk];
    }
}

// ---------------------------------------------------------------- K2: collapsed scan, 2 units/block, split accumulators
// y_t = y_{t-1} + invM*(x_t - y_{t-1}); y in fp32 registers; d fp16 via dbuf dL.
// 1024 threads = 16 waves (4/SIMD): waves 0-7 run unit (b,dc), waves 8-15 run
// (b,dc+1) — two INDEPENDENT recurrences sharing one barrier; 4 streams/SIMD
// interleave each other's ds_read/MFMA/VMEM latencies (r7-r10 flat ~2200cyc
// step = latency dead time, not pipe throughput).
// MFMA: separate accumulators per k-slice (chain depth 4 -> 1); H0 seeded
// with y (free C-input); VALU tree-sum afterwards.
__global__ __launch_bounds__(1024, 4) void k_scan(const float* __restrict__ invMt,
                                                  const float* __restrict__ xs,
                                                  float* __restrict__ out) {
    __shared__ __align__(16) _Float16 dL[2][2][8][KSTR];   // 8.5 KB

    const int bid = blockIdx.x;
    const int xcd = bid & 7, g = bid >> 3;
    const int dcg = g & 3, b = (xcd << 2) | (g >> 2);   // dcg-siblings share an XCD
    const int tid = threadIdx.x;
    const int w = tid >> 6, l = tid & 63;
    const int s = w >> 3;        // sub-unit (column group dc = dcg*2 + s)
    const int wr = w & 7;        // row-tile within sub-unit
    const int cl = l & 15;       // MFMA col slot; real col = (cl&7)
    const int h = l >> 4;        // k-subgroup (0..3) / D-row-group
    const bool io = (cl < 8);    // lanes that own a real column

    // ---- preload invM A-frags (rows R = 16*wr+cl), hi/lo split; kappa(h,e)=8h+e
    f16x8 VHi[4], VLo[4];
    {
        const float* Vb = invMt + b * NN * NN;
        const int R = wr * 16 + cl;
        #pragma unroll
        for (int ks = 0; ks < 4; ++ks) {
            #pragma unroll
            for (int e = 0; e < 8; ++e) {
                const int k = ks * 32 + h * 8 + e;
                float gv = Vb[k * NN + R];              // invMt[k][R] = invM[R][k]
                _Float16 gh = (_Float16)gv;
                VHi[ks][e] = gh;
                VLo[ks][e] = (_Float16)((gv - (float)gh) * 4096.0f);
            }
        }
    }

    const int tstr = NN * DD;
    const size_t base = (size_t)b * TT * tstr + (dcg * 2 + s) * 8 + (cl & 7);
    const float* xbase = xs + base;
    float* obase = out + base;
    int roff[4];
    #pragma unroll
    for (int j = 0; j < 4; ++j)
        roff[j] = (wr * 16 + h * 4 + j) * DD;   // D-layout rows of this lane
    const int yrow = wr * 16 + h * 4;

    float y[4] = {0.f, 0.f, 0.f, 0.f};
    float xsl[4][4];   // slot q holds x_{t'} with t' ≡ q (mod 4); static indexing only

    // ---- prologue: d_0 = x_0 (y_{-1}=0); fill slots with x_1..x_4
    {
        float x0r[4] = {0.f, 0.f, 0.f, 0.f};
        if (io) {
            #pragma unroll
            for (int j = 0; j < 4; ++j) x0r[j] = xbase[roff[j]];
            #pragma unroll
            for (int j = 0; j < 4; ++j) xsl[1][j] = xbase[1 * tstr + roff[j]];
            #pragma unroll
            for (int j = 0; j < 4; ++j) xsl[2][j] = xbase[2 * tstr + roff[j]];
            #pragma unroll
            for (int j = 0; j < 4; ++j) xsl[3][j] = xbase[3 * tstr + roff[j]];
            #pragma unroll
            for (int j = 0; j < 4; ++j) xsl[0][j] = xbase[4 * tstr + roff[j]];
            f16x4 p;
            #pragma unroll
            for (int j = 0; j < 4; ++j) p[j] = (_Float16)x0r[j];
            *(f16x4*)&dL[0][s][cl][yrow] = p;
        }
        LBAR();   // d_0 visible
    }

    // ---- main loop: step t reads dL[t&1][s], publishes d_{t+1} into dL[(t+1)&1][s]
    for (int i = 0; i < TT / 4; ++i) {
        #pragma unroll
        for (int u = 0; u < 4; ++u) {
            const int t = 4 * i + u;
            const int pr = u & 1, pw = pr ^ 1;   // t&1 == u&1 (4i even)
            const int sl = (u + 1) & 3;          // slot holding x_{t+1}

            // m = invM * d_t : 8 INDEPENDENT MFMAs (4 H + 4 L), H0 seeded with y
            f32x4v aH[4], aL[4];
            #pragma unroll
            for (int ks = 0; ks < 4; ++ks) {
                f32x4v z = {0.f, 0.f, 0.f, 0.f};
                aH[ks] = z; aL[ks] = z;
            }
            aH[0][0] = y[0]; aH[0][1] = y[1]; aH[0][2] = y[2]; aH[0][3] = y[3];
            #pragma unroll
            for (int ks = 0; ks < 4; ++ks) {
                f16x8 bf = *(const f16x8*)&dL[pr][s][cl & 7][ks * 32 + h * 8];
                aH[ks] = __builtin_amdgcn_mfma_f32_16x16x32_f16(VHi[ks], bf, aH[ks], 0, 0, 0);
                aL[ks] = __builtin_amdgcn_mfma_f32_16x16x32_f16(VLo[ks], bf, aL[ks], 0, 0, 0);
            }
            f32x4v H = (aH[0] + aH[1]) + (aH[2] + aH[3]);
            f32x4v L = (aL[0] + aL[1]) + (aL[2] + aL[3]);
            #pragma unroll
            for (int j = 0; j < 4; ++j)
                y[j] = __builtin_fmaf(L[j], 1.0f / 4096.0f, H[j]);

            // store y_t (fire-and-forget; barriers never drain vmcnt)
            if (io) {
                #pragma unroll
                for (int j = 0; j < 4; ++j) obase[t * tstr + roff[j]] = y[j];
            }

            if (u != 3 || i != TT / 4 - 1) {     // all but the very last step
                if (io) {
                    // publish d_{t+1} = x_{t+1} - y_t
                    f16x4 p;
                    #pragma unroll
                    for (int j = 0; j < 4; ++j) p[j] = (_Float16)(xsl[sl][j] - y[j]);
                    *(f16x4*)&dL[pw][s][cl][yrow] = p;
                    // refill the freed slot with x_{t+5} (consumed at step t+4)
                    const int tl = (t + 5 < TT) ? (t + 5) : (TT - 1);
                    #pragma unroll
                    for (int j = 0; j < 4; ++j) xsl[sl][j] = xbase[tl * tstr + roff[j]];
                }
                LBAR();
            }
        }
    }
}

// ----------------------------------------------------------------
extern "C" void kernel_launch(void* const* d_in, const int* in_sizes, int n_in,
                              void* d_out, int out_size, void* d_ws, size_t ws_size,
                              hipStream_t stream) {
    const float* xs = (const float*)d_in[0];   // [32,256,128,64]
    const float* A  = (const float*)d_in[1];   // [32,128,128]
    float* out = (float*)d_out;                // [32,256,128,64]
    float* ws = (float*)d_ws;                  // needs 2 MB

    float* invMt = ws;                          // invM^T per batch [32][128][128]

    k_prep <<<BB, 256, 0, stream>>>(A, invMt);
    k_scan <<<BB * 4, 1024, 0, stream>>>(invMt, xs, out);
}